// Round 6
// baseline (2834.532 us; speedup 1.0000x reference)
//
#include <hip/hip_runtime.h>
#include <math.h>

#define M_NODES 1000
#define L_EDGES 499500
#define GROUPS  500      // row pairs (g, 998-g); g==499 is self-paired (row 499)
#define NG      16       // group-pairs per chunk/block
#define CHUNKS  32       // ceil(GROUPS/NG); last chunk has 4 pairs
#define CPAD    32       // padded chunk stride for transposed partials [b][i][CPAD]

// LDS anti-conflict swizzle: bijective, spreads the lane-stride-4 (16B)
// access pattern of the strip loop across banks (<=2-way).
#define IDX(i) ((i) ^ (((i) >> 5) & 3))

__device__ __forceinline__ float wave_sum(float v){
  #pragma unroll
  for (int o = 32; o > 0; o >>= 1) v += __shfl_down(v, o);
  return v;
}

// One dispatch per time step t = 0..T (16 total, was 31).
//   prologue (t>=1): node update N_{t-1} recomputed REDUNDANTLY per block from
//     v_{t-1} (global) + partials_{t-1} (global, transposed [b][i][CPAD]):
//     p2_{t-1} -> pp, v_t -> vc (and vp = v_{t-1}). Deterministic arithmetic
//     -> bit-identical across blocks. Block c==0 persists v_t to global.
//   edge phase: C_{t-1} (w_t update, write out[t-1]) when t>=1,
//               A_t (p1_t, DT partials into sA/sB) when t<T.
//   epilogue (t<T): write this block's partial column c (double-buffered by
//     t-parity: same-dispatch blocks read old parity, write new -> no race).
__global__ __launch_bounds__(256) void fused_pass(
    const float* __restrict__ z, float* __restrict__ out,
    const float* __restrict__ vprev_g, float* __restrict__ vcur_g,
    const float* __restrict__ pAin, const float* __restrict__ pBin,
    float* __restrict__ pAout, float* __restrict__ pBout,
    const float* __restrict__ gn_p, const float* __restrict__ alpha_p,
    const float* __restrict__ beta_p, int t, int T)
{
  const int b   = blockIdx.x / CHUNKS;
  const int c   = blockIdx.x % CHUNKS;
  const int tid = threadIdx.x;
  const float gn    = gn_p[0];
  const float alpha = alpha_p[0];
  const float beta  = beta_p[0];
  const float c1 = 1.f - 2.f * gn * beta;
  const float g2 = 2.f * gn;
  const bool has_c = (t >= 1);
  const bool has_a = (t < T);
  const bool has_w = (t >= 2);

  __shared__ float vp[M_NODES];  // v_{t-1}   (swizzled)
  __shared__ float vc[M_NODES];  // v_t       (swizzled)
  __shared__ float pp[M_NODES];  // p2_{t-1}  (swizzled)
  __shared__ float sA[M_NODES];  // partial DT(w_t)   (swizzled)
  __shared__ float sB[M_NODES];  // partial DT(p1_t)  (swizzled)

  for (int i = tid; i < M_NODES; i += 256){ sA[i] = 0.f; sB[i] = 0.f; }

  const int g0 = c * NG;

  if (t == 0){
    // v_0 = 0; block c==0 also materializes it for the t=1 prologue.
    for (int i = tid; i < M_NODES; i += 256){
      vc[IDX(i)] = 0.f;
      if (c == 0) vcur_g[b * M_NODES + i] = 0.f;
    }
  } else {
    // node phase N_{t-1}, nodes i >= g0 (this block only touches i >= g0).
    for (int i = g0 + tid; i < M_NODES; i += 256){
      const int cmax = ((i >> 4) < CHUNKS - 1) ? (i >> 4) : (CHUNKS - 1);
      const float* rowA = pAin + ((size_t)b * M_NODES + i) * CPAD;
      const float* rowB = pBin + ((size_t)b * M_NODES + i) * CPAD;
      float a0 = 0.f, a1 = 0.f, a2 = 0.f, a3 = 0.f;
      float b0 = 0.f, b1 = 0.f, b2 = 0.f, b3 = 0.f;
      int cc = 0;
      for (; cc + 3 <= cmax; cc += 4){
        const float4 va4 = *(const float4*)(rowA + cc);
        const float4 vb4 = *(const float4*)(rowB + cc);
        a0 += va4.x; b0 += vb4.x;
        a1 += va4.y; b1 += vb4.y;
        a2 += va4.z; b2 += vb4.z;
        a3 += va4.w; b3 += vb4.w;
      }
      for (; cc <= cmax; ++cc){ a0 += rowA[cc]; b0 += rowB[cc]; }
      const float sw = (a0 + a1) + (a2 + a3);
      const float sp = (b0 + b1) + (b2 + b3);
      const float v  = vprev_g[b * M_NODES + i];
      const float y2 = v + gn * sw;
      const float up = fmaxf(y2 * y2 + 4.f * gn * alpha, 1e-8f);
      const float p2v = 0.5f * (y2 - sqrtf(up));
      vp[IDX(i)] = v;
      pp[IDX(i)] = p2v;
      const float vn = p2v + gn * (sp - sw);
      vc[IDX(i)] = vn;
      if (c == 0) vcur_g[b * M_NODES + i] = vn;   // persist v_t for next dispatch
    }
  }
  __syncthreads();

  const float* zb    = z + (size_t)b * L_EDGES;
  const float* wprev = has_w ? out + ((size_t)b * T + (t - 2)) * L_EDGES : nullptr;
  float*       wout  = has_c ? out + ((size_t)b * T + (t - 1)) * L_EDGES : nullptr;

  const int g1 = (g0 + NG < GROUPS) ? (g0 + NG) : GROUPS;

  for (int g = g0; g < g1; ++g){
    #pragma unroll
    for (int half = 0; half < 2; ++half){
      const int r = half ? (998 - g) : g;
      if (half && r == g) break;          // self-paired row (g == 499)
      const int n    = 999 - r;           // edges in row r
      const int base = r * 999 - (r * (r - 1)) / 2;
      float vpr = 0.f, ppr = 0.f, vcr = 0.f;
      if (has_c){ vpr = vp[IDX(r)]; ppr = pp[IDX(r)]; }
      if (has_a){ vcr = vc[IDX(r)]; }

      float pw = 0.f, pq = 0.f;           // row-sum partials for s[r]

      // alignment decomposition of [0, n): a0 scalar + 4*strips vector + epi scalar
      const int a0m    = (4 - (base & 3)) & 3;
      const int a0     = (a0m < n) ? a0m : n;
      const int strips = (n - a0) >> 2;
      const int epi    = n - a0 - (strips << 2);

      auto edge1 = [&](int k){
        const int e = base + k;
        const int j = r + 1 + k;
        const float ze = zb[e];
        float w_new = 0.f;
        if (has_c){
          const float w_old = has_w ? wprev[e] : 0.f;
          const float y1 = w_old * c1 - gn * (vpr + vp[IDX(j)]);
          const float p1 = fmaxf(0.f, y1 - g2 * ze);
          const float q1 = p1 * c1 - gn * (ppr + pp[IDX(j)]);
          w_new = w_old - y1 + q1;
          wout[e] = w_new;
        }
        if (has_a){
          const float y1n = w_new * c1 - gn * (vcr + vc[IDX(j)]);
          const float p1n = fmaxf(0.f, y1n - g2 * ze);
          pw += w_new; pq += p1n;
          atomicAdd(&sA[IDX(j)], w_new);
          atomicAdd(&sB[IDX(j)], p1n);
        }
      };
      if (tid < a0) edge1(tid);
      if (tid >= 4 && tid < 4 + epi) edge1(a0 + (strips << 2) + (tid - 4));

      for (int s = tid; s < strips; s += 256){
        const int k = a0 + (s << 2);
        const int e = base + k;            // e % 4 == 0
        const int j = r + 1 + k;
        const float4 zv = *(const float4*)(zb + e);
        float w0, w1, w2, w3;
        if (has_c){
          float4 wv;
          if (has_w) wv = *(const float4*)(wprev + e);
          else { wv.x = 0.f; wv.y = 0.f; wv.z = 0.f; wv.w = 0.f; }
          const float y10 = wv.x * c1 - gn * (vpr + vp[IDX(j    )]);
          const float y11 = wv.y * c1 - gn * (vpr + vp[IDX(j + 1)]);
          const float y12 = wv.z * c1 - gn * (vpr + vp[IDX(j + 2)]);
          const float y13 = wv.w * c1 - gn * (vpr + vp[IDX(j + 3)]);
          const float p10 = fmaxf(0.f, y10 - g2 * zv.x);
          const float p11 = fmaxf(0.f, y11 - g2 * zv.y);
          const float p12 = fmaxf(0.f, y12 - g2 * zv.z);
          const float p13 = fmaxf(0.f, y13 - g2 * zv.w);
          const float q10 = p10 * c1 - gn * (ppr + pp[IDX(j    )]);
          const float q11 = p11 * c1 - gn * (ppr + pp[IDX(j + 1)]);
          const float q12 = p12 * c1 - gn * (ppr + pp[IDX(j + 2)]);
          const float q13 = p13 * c1 - gn * (ppr + pp[IDX(j + 3)]);
          w0 = wv.x - y10 + q10;
          w1 = wv.y - y11 + q11;
          w2 = wv.z - y12 + q12;
          w3 = wv.w - y13 + q13;
          float4 wo; wo.x = w0; wo.y = w1; wo.z = w2; wo.w = w3;
          *(float4*)(wout + e) = wo;
        } else { w0 = w1 = w2 = w3 = 0.f; }
        if (has_a){
          const float yn0 = w0 * c1 - gn * (vcr + vc[IDX(j    )]);
          const float yn1 = w1 * c1 - gn * (vcr + vc[IDX(j + 1)]);
          const float yn2 = w2 * c1 - gn * (vcr + vc[IDX(j + 2)]);
          const float yn3 = w3 * c1 - gn * (vcr + vc[IDX(j + 3)]);
          const float pn0 = fmaxf(0.f, yn0 - g2 * zv.x);
          const float pn1 = fmaxf(0.f, yn1 - g2 * zv.y);
          const float pn2 = fmaxf(0.f, yn2 - g2 * zv.z);
          const float pn3 = fmaxf(0.f, yn3 - g2 * zv.w);
          pw += (w0 + w1) + (w2 + w3);
          pq += (pn0 + pn1) + (pn2 + pn3);
          atomicAdd(&sA[IDX(j    )], w0); atomicAdd(&sB[IDX(j    )], pn0);
          atomicAdd(&sA[IDX(j + 1)], w1); atomicAdd(&sB[IDX(j + 1)], pn1);
          atomicAdd(&sA[IDX(j + 2)], w2); atomicAdd(&sB[IDX(j + 2)], pn2);
          atomicAdd(&sA[IDX(j + 3)], w3); atomicAdd(&sB[IDX(j + 3)], pn3);
        }
      }

      if (has_a){
        pw = wave_sum(pw);
        pq = wave_sum(pq);
        if ((tid & 63) == 0){
          atomicAdd(&sA[IDX(r)], pw);
          atomicAdd(&sB[IDX(r)], pq);
        }
      }
    }
  }

  if (has_a){
    __syncthreads();
    // transposed partial write: pout[b][i][c]; this chunk only touches i >= g0.
    float* pA = pAout + (size_t)b * M_NODES * CPAD;
    float* pB = pBout + (size_t)b * M_NODES * CPAD;
    for (int i = g0 + tid; i < M_NODES; i += 256){
      pA[(size_t)i * CPAD + c] = sA[IDX(i)];
      pB[(size_t)i * CPAD + c] = sB[IDX(i)];
    }
  }
}

extern "C" void kernel_launch(void* const* d_in, const int* in_sizes, int n_in,
                              void* d_out, int out_size, void* d_ws, size_t ws_size,
                              hipStream_t stream)
{
  const float* z     = (const float*)d_in[0];
  const float* gn    = (const float*)d_in[1];
  const float* alpha = (const float*)d_in[2];
  const float* beta  = (const float*)d_in[3];
  const int B = in_sizes[0] / L_EDGES;      // 16
  const int T = out_size / in_sizes[0];     // 15
  float* out = (float*)d_out;

  const size_t BM  = (size_t)B * M_NODES;
  const size_t BMC = (size_t)B * M_NODES * CPAD;
  float* ws  = (float*)d_ws;
  float* va  = ws;             // v buffer parity 0
  float* vb  = va + BM;        // v buffer parity 1
  float* pA0 = vb + BM;        // partials A, parity 0
  float* pB0 = pA0 + BMC;
  float* pA1 = pB0 + BMC;      // partials A, parity 1
  float* pB1 = pA1 + BMC;

  float* vbuf[2]  = { va, vb };
  float* partsA[2] = { pA0, pA1 };
  float* partsB[2] = { pB0, pB1 };

  const dim3 egrid(B * CHUNKS);   // 512 blocks

  // 16 dispatches: t=0 A-only (+v0 init); t=1..T-1 fused N_{t-1}+C_{t-1}+A_t;
  // t=T fused N_{T-1}+C_{T-1}.
  for (int t = 0; t <= T; ++t){
    const float* vprev = vbuf[(t + 1) & 1];       // v_{t-1} (unused at t=0)
    float*       vcur  = vbuf[t & 1];             // v_t (written by c==0)
    const float* pAin  = partsA[(t + 1) & 1];     // partials_{t-1} (unused at t=0)
    const float* pBin  = partsB[(t + 1) & 1];
    float*       pAout = partsA[t & 1];           // partials_t (unused at t=T)
    float*       pBout = partsB[t & 1];
    hipLaunchKernelGGL(fused_pass, egrid, dim3(256), 0, stream,
                       z, out, vprev, vcur, pAin, pBin, pAout, pBout,
                       gn, alpha, beta, t, T);
  }
}